// Round 3
// baseline (19.698 us; speedup 1.0000x reference)
//
#include <hip/hip_runtime.h>

#define W    16                  // CHUNK
#define OPT  4                   // outputs per thread
#define NTHR 256                 // threads per block
#define TILE (OPT * NTHR)        // 1024 outputs per block

// out[b,t] = E[t] * sum_{k=0..15} emit[t+k] / S[t+k]
//   E[j] = exp(logits[j])  (0 outside [0,T))
//   S[u] = sum_{j=u-15..u} E[j]
// Pure-register version: no LDS, no barriers. Each thread owns outputs
// t..t+3 and recomputes its own halo (E over [t-16, t+19]).
__global__ __launch_bounds__(NTHR)
void mocha_chunkwise_kernel(const float* __restrict__ emit,
                            const float* __restrict__ logits,
                            float* __restrict__ out,
                            int T)
{
    const int b  = blockIdx.y;
    const int t0 = blockIdx.x * TILE;
    const int t  = t0 + OPT * (int)threadIdx.x;

    const float* lrow = logits + (size_t)b * T;
    const float* erow = emit   + (size_t)b * T;
    float*       orow = out    + (size_t)b * T;

    float e[36];    // e[k]  = E[t-16+k],  k in [0,36)
    float em[20];   // em[i] = emit[t+i],  i in [0,20) (19 used)

    if (t0 >= W && t0 + TILE + (W - 1) <= T) {
        // ---- fast path (interior tile): everything in-bounds, aligned f4 ----
        float4 lv[9], ev[5];
        #pragma unroll
        for (int q = 0; q < 9; ++q)
            lv[q] = *reinterpret_cast<const float4*>(lrow + (t - W) + 4 * q);
        #pragma unroll
        for (int q = 0; q < 5; ++q)
            ev[q] = *reinterpret_cast<const float4*>(erow + t + 4 * q);

        #pragma unroll
        for (int q = 0; q < 9; ++q) {
            e[4*q+0] = __expf(lv[q].x); e[4*q+1] = __expf(lv[q].y);
            e[4*q+2] = __expf(lv[q].z); e[4*q+3] = __expf(lv[q].w);
        }
        #pragma unroll
        for (int q = 0; q < 5; ++q) {
            em[4*q+0] = ev[q].x; em[4*q+1] = ev[q].y;
            em[4*q+2] = ev[q].z; em[4*q+3] = ev[q].w;
        }
    } else {
        // ---- slow path (first/last tile of each row): guarded scalar ----
        #pragma unroll
        for (int k = 0; k < 36; ++k) {
            const int j = t - W + k;
            e[k] = (j >= 0 && j < T) ? __expf(lrow[j]) : 0.0f;
        }
        #pragma unroll
        for (int i = 0; i < 20; ++i) {
            const int u = t + i;
            em[i] = (u < T) ? erow[u] : 0.0f;
        }
    }

    // g[i] = emit[t+i] / S[t+i];  S[t+i] = sum_{k=1..16} e[i+k]
    float g[OPT + W - 1];   // 19
    #pragma unroll
    for (int i = 0; i < OPT + W - 1; ++i) {
        float S = 0.0f;
        #pragma unroll
        for (int k = 1; k <= W; ++k) S += e[i + k];
        const float gg = __fdividef(em[i], S);
        g[i] = (t + i < T) ? gg : 0.0f;   // guard: S==0 -> NaN when u>=T
    }

    float r[OPT];
    #pragma unroll
    for (int rr = 0; rr < OPT; ++rr) {
        float acc = 0.0f;
        #pragma unroll
        for (int k = 0; k < W; ++k) acc += g[rr + k];
        r[rr] = e[W + rr] * acc;          // e[16+rr] = E[t+rr]
    }

    if (t + OPT - 1 < T) {
        *reinterpret_cast<float4*>(orow + t) = make_float4(r[0], r[1], r[2], r[3]);
    } else {
        #pragma unroll
        for (int rr = 0; rr < OPT; ++rr)
            if (t + rr < T) orow[t + rr] = r[rr];
    }
}

extern "C" void kernel_launch(void* const* d_in, const int* in_sizes, int n_in,
                              void* d_out, int out_size, void* d_ws, size_t ws_size,
                              hipStream_t stream)
{
    const float* emit   = (const float*)d_in[0];   // emit_probs     [B,T]
    const float* logits = (const float*)d_in[1];   // softmax_logits [B,T]
    float*       out    = (float*)d_out;           // [B,T] fp32

    const int T = 16384;
    const int B = in_sizes[0] / T;                 // 64

    dim3 grid(T / TILE, B);                        // 16 x 64 = 1024 blocks
    dim3 block(NTHR);
    mocha_chunkwise_kernel<<<grid, block, 0, stream>>>(emit, logits, out, T);
}

// Round 4
// 10.313 us; speedup vs baseline: 1.9099x; 1.9099x over previous
//
#include <hip/hip_runtime.h>

#define W    16                  // CHUNK
#define OPT  4                   // outputs per thread
#define NTHR 256                 // threads per block
#define TILE (OPT * NTHR)        // 1024 outputs per block

// out[b,t] = E[t] * sum_{k=0..15} emit[t+k] / S[t+k]
//   E[j] = exp(logits[j])  (0 outside [0,T))
//   S[u] = sum_{j=u-15..u} E[j]
// Single-barrier version: both inputs staged to LDS, all global loads
// issued back-to-back at kernel entry so the two cold-memory latencies
// overlap. Compute uses rolling sliding-window sums.
__global__ __launch_bounds__(NTHR)
void mocha_chunkwise_kernel(const float* __restrict__ emit,
                            const float* __restrict__ logits,
                            float* __restrict__ out,
                            int T)
{
    const int b   = blockIdx.y;
    const int t0  = blockIdx.x * TILE;
    const int tid = threadIdx.x;

    const float* lrow = logits + (size_t)b * T;
    const float* erow = emit   + (size_t)b * T;
    float*       orow = out    + (size_t)b * T;

    __shared__ float Es[TILE + 2 * W];   // Es[i] = E[t0-16+i],  i in [0,1056)
    __shared__ float Em[TILE + W];       // Em[i] = emit[t0+i],  i in [0,1040)

    // ---------- issue ALL global loads first (overlap cold latencies) ----
    const int i0 = 4 * tid;              // Es chunk A
    const int j0 = t0 - W + i0;
    const bool l0f = (j0 >= 0) && (j0 + 3 < T);
    float4 lv0, lv1, ev0, ev1;
    if (l0f) lv0 = *reinterpret_cast<const float4*>(lrow + j0);

    const int  i1  = 4 * (NTHR + tid);   // Es chunk B (tid<8 only)
    const int  j1  = t0 - W + i1;
    const bool do1 = (tid < (TILE + 2 * W - 4 * NTHR) / 4);   // tid < 8
    const bool l1f = do1 && (j1 >= 0) && (j1 + 3 < T);
    if (l1f) lv1 = *reinterpret_cast<const float4*>(lrow + j1);

    const int  u0  = t0 + 4 * tid;       // Em chunk A
    const bool e0f = (u0 + 3 < T);
    if (e0f) ev0 = *reinterpret_cast<const float4*>(erow + u0);

    const int  u1   = t0 + 4 * (NTHR + tid);  // Em chunk B (tid<4 only)
    const bool doE1 = (tid < (TILE + W - 4 * NTHR) / 4);      // tid < 4
    const bool e1f  = doE1 && (u1 + 3 < T);
    if (e1f) ev1 = *reinterpret_cast<const float4*>(erow + u1);

    // ---------- slow-path gathers (edge blocks only) ----------
    float la0[4], la1[4], ea0[4], ea1[4];
    if (l0f) { la0[0]=lv0.x; la0[1]=lv0.y; la0[2]=lv0.z; la0[3]=lv0.w; }
    else {
        #pragma unroll
        for (int q = 0; q < 4; ++q) {
            const int j = j0 + q;
            la0[q] = (j >= 0 && j < T) ? lrow[j] : 0.0f;   // flag via E=0 below
        }
    }
    if (l1f) { la1[0]=lv1.x; la1[1]=lv1.y; la1[2]=lv1.z; la1[3]=lv1.w; }
    else if (do1) {
        #pragma unroll
        for (int q = 0; q < 4; ++q) {
            const int j = j1 + q;
            la1[q] = (j >= 0 && j < T) ? lrow[j] : 0.0f;
        }
    }
    if (e0f) { ea0[0]=ev0.x; ea0[1]=ev0.y; ea0[2]=ev0.z; ea0[3]=ev0.w; }
    else {
        #pragma unroll
        for (int q = 0; q < 4; ++q) {
            const int u = u0 + q;
            ea0[q] = (u < T) ? erow[u] : 0.0f;
        }
    }
    if (e1f) { ea1[0]=ev1.x; ea1[1]=ev1.y; ea1[2]=ev1.z; ea1[3]=ev1.w; }
    else if (doE1) {
        #pragma unroll
        for (int q = 0; q < 4; ++q) {
            const int u = u1 + q;
            ea1[q] = (u < T) ? erow[u] : 0.0f;
        }
    }

    // ---------- exp + LDS stores ----------
    {
        float4 v;
        v.x = (j0 + 0 >= 0 && j0 + 0 < T) ? __expf(la0[0]) : 0.0f;
        v.y = (j0 + 1 >= 0 && j0 + 1 < T) ? __expf(la0[1]) : 0.0f;
        v.z = (j0 + 2 >= 0 && j0 + 2 < T) ? __expf(la0[2]) : 0.0f;
        v.w = (j0 + 3 >= 0 && j0 + 3 < T) ? __expf(la0[3]) : 0.0f;
        *reinterpret_cast<float4*>(Es + i0) = v;
    }
    if (do1) {
        float4 v;
        v.x = (j1 + 0 >= 0 && j1 + 0 < T) ? __expf(la1[0]) : 0.0f;
        v.y = (j1 + 1 >= 0 && j1 + 1 < T) ? __expf(la1[1]) : 0.0f;
        v.z = (j1 + 2 >= 0 && j1 + 2 < T) ? __expf(la1[2]) : 0.0f;
        v.w = (j1 + 3 >= 0 && j1 + 3 < T) ? __expf(la1[3]) : 0.0f;
        *reinterpret_cast<float4*>(Es + i1) = v;
    }
    *reinterpret_cast<float4*>(Em + 4 * tid) =
        make_float4(ea0[0], ea0[1], ea0[2], ea0[3]);
    if (doE1)
        *reinterpret_cast<float4*>(Em + 4 * (NTHR + tid)) =
            make_float4(ea1[0], ea1[1], ea1[2], ea1[3]);

    __syncthreads();   // the ONLY barrier

    // ---------- compute 4 outputs from LDS ----------
    // e[m] = Es[4*tid + m], m in [0,36); em[i] = Em[4*tid + i], i in [0,20)
    float e[36], em[20];
    #pragma unroll
    for (int q = 0; q < 9; ++q) {
        float4 v = *reinterpret_cast<const float4*>(Es + i0 + 4 * q);
        e[4*q+0] = v.x; e[4*q+1] = v.y; e[4*q+2] = v.z; e[4*q+3] = v.w;
    }
    #pragma unroll
    for (int q = 0; q < 5; ++q) {
        float4 v = *reinterpret_cast<const float4*>(Em + i0 + 4 * q);
        em[4*q+0] = v.x; em[4*q+1] = v.y; em[4*q+2] = v.z; em[4*q+3] = v.w;
    }

    // S_j = sum e[j+1 .. j+16]  (= S[t+j]);  rolling update.
    // g[j] = em[j] / S_j.  (em staged 0 for u>=T; S_j>0 within range.)
    float g[OPT + W - 1];                     // 19
    float S = 0.0f;
    #pragma unroll
    for (int k = 1; k <= W; ++k) S += e[k];
    #pragma unroll
    for (int j = 0; j < OPT + W - 1; ++j) {
        g[j] = __fdividef(em[j], S);
        if (j < OPT + W - 2) S += e[j + 17] - e[j + 1];
    }

    // out[t+r] = e[16+r] * sum_{k=0..15} g[r+k]; rolling update.
    float acc = 0.0f;
    #pragma unroll
    for (int k = 0; k < W; ++k) acc += g[k];
    float r[OPT];
    r[0] = e[W] * acc;
    #pragma unroll
    for (int rr = 1; rr < OPT; ++rr) {
        acc += g[rr + W - 1] - g[rr - 1];
        r[rr] = e[W + rr] * acc;
    }

    const int t = t0 + i0;
    if (t + OPT - 1 < T) {
        *reinterpret_cast<float4*>(orow + t) = make_float4(r[0], r[1], r[2], r[3]);
    } else {
        #pragma unroll
        for (int rr = 0; rr < OPT; ++rr)
            if (t + rr < T) orow[t + rr] = r[rr];
    }
}

extern "C" void kernel_launch(void* const* d_in, const int* in_sizes, int n_in,
                              void* d_out, int out_size, void* d_ws, size_t ws_size,
                              hipStream_t stream)
{
    const float* emit   = (const float*)d_in[0];   // emit_probs     [B,T]
    const float* logits = (const float*)d_in[1];   // softmax_logits [B,T]
    float*       out    = (float*)d_out;           // [B,T] fp32

    const int T = 16384;
    const int B = in_sizes[0] / T;                 // 64

    dim3 grid(T / TILE, B);                        // 16 x 64 = 1024 blocks
    dim3 block(NTHR);
    mocha_chunkwise_kernel<<<grid, block, 0, stream>>>(emit, logits, out, T);
}